// Round 1
// baseline (101.282 us; speedup 1.0000x reference)
//
#include <hip/hip_runtime.h>

// ForwardTransformLayer: circular DWT analysis step.
//   details[r][j] = sum_k w[k] * in[r][(2j - k) mod M]
//   approx [r][j] = sum_k h[k] * in[r][(2j - k) mod M]
// with h = scaling (8 taps), w[k] = h[7-k] * (-1)^k (QMF).
// Memory-bound: 256 MiB read + 256 MiB write.

#define N_ROWS   4096
#define SIG_LEN  16384
#define HALF_LEN (SIG_LEN / 2)
#define THREADS_PER_ROW (HALF_LEN / 8)   // 1024: each thread -> 8 output cols

__global__ __launch_bounds__(256) void dwt_fwd_kernel(
    const float* __restrict__ input,
    const float* __restrict__ scaling,
    float* __restrict__ details,
    float* __restrict__ approx)
{
    const int tid = blockIdx.x * blockDim.x + threadIdx.x;   // < 4096*1024, fits int
    const int row = tid >> 10;          // THREADS_PER_ROW == 1024
    const int seg = tid & 1023;
    if (row >= N_ROWS) return;

    // Filter taps: uniform address -> compiler emits scalar loads (L1-broadcast).
    float h[8], w[8];
#pragma unroll
    for (int k = 0; k < 8; ++k) h[k] = scaling[k];
#pragma unroll
    for (int k = 0; k < 8; ++k) w[k] = h[7 - k] * ((k & 1) ? -1.0f : 1.0f);

    const int i0 = seg << 4;                         // first input sample of this thread
    const float* rowp = input + (size_t)row * SIG_LEN;

    // x[0..23] covers input[i0-8 .. i0+15] (circular halo on the left).
    float x[24];

    // Halo: two aligned float4 loads; wraps only for seg==0.
    {
        const int hbase = (i0 == 0) ? (SIG_LEN - 8) : (i0 - 8);
        const float4 a = *reinterpret_cast<const float4*>(rowp + hbase);
        const float4 b = *reinterpret_cast<const float4*>(rowp + hbase + 4);
        x[0] = a.x; x[1] = a.y; x[2] = a.z; x[3] = a.w;
        x[4] = b.x; x[5] = b.y; x[6] = b.z; x[7] = b.w;
    }
    // Main 16 samples: four aligned float4 loads (fully coalesced across threads).
#pragma unroll
    for (int q = 0; q < 4; ++q) {
        const float4 v = *reinterpret_cast<const float4*>(rowp + i0 + 4 * q);
        x[8 + 4 * q + 0] = v.x;
        x[8 + 4 * q + 1] = v.y;
        x[8 + 4 * q + 2] = v.z;
        x[8 + 4 * q + 3] = v.w;
    }

    float det[8], app[8];
#pragma unroll
    for (int j = 0; j < 8; ++j) {
        const int base = 8 + 2 * j;     // x[base] == input[i0 + 2j]
        float d = 0.0f, a = 0.0f;
#pragma unroll
        for (int k = 0; k < 8; ++k) {
            const float xi = x[base - k];
            d = fmaf(w[k], xi, d);
            a = fmaf(h[k], xi, a);
        }
        det[j] = d;
        app[j] = a;
    }

    const size_t obase = (size_t)row * HALF_LEN + (size_t)(seg << 3);
    float4* dp = reinterpret_cast<float4*>(details + obase);
    float4* ap = reinterpret_cast<float4*>(approx + obase);
    dp[0] = make_float4(det[0], det[1], det[2], det[3]);
    dp[1] = make_float4(det[4], det[5], det[6], det[7]);
    ap[0] = make_float4(app[0], app[1], app[2], app[3]);
    ap[1] = make_float4(app[4], app[5], app[6], app[7]);
}

extern "C" void kernel_launch(void* const* d_in, const int* in_sizes, int n_in,
                              void* d_out, int out_size, void* d_ws, size_t ws_size,
                              hipStream_t stream) {
    const float* input   = (const float*)d_in[0];
    const float* scaling = (const float*)d_in[1];
    float* details = (float*)d_out;                                   // output 0
    float* approx  = (float*)d_out + (size_t)N_ROWS * HALF_LEN;       // output 1

    const int total_threads = N_ROWS * THREADS_PER_ROW;               // 4,194,304
    const int block = 256;
    const int grid  = total_threads / block;                          // 16,384
    dwt_fwd_kernel<<<grid, block, 0, stream>>>(input, scaling, details, approx);
}

// Round 3
// 81.768 us; speedup vs baseline: 1.2387x; 1.2387x over previous
//
#include <hip/hip_runtime.h>

// ForwardTransformLayer: circular DWT analysis step.
//   details[r][j] = sum_k w[k] * in[r][(2j - k) mod M]
//   approx [r][j] = sum_k h[k] * in[r][(2j - k) mod M]
// with h = scaling (8 taps), w[k] = h[7-k] * (-1)^k (QMF).
//
// Memory-bound: 256 MiB read + 256 MiB write. Every VMEM instruction is
// unit-stride across the wave (16B/lane loads, 8B/lane stores). Halo comes
// from two overlapping unit-stride float4 loads that hit L1. Output stores
// are nontemporal (streamed, never re-read).

#define N_ROWS   4096
#define SIG_LEN  16384
#define HALF_LEN (SIG_LEN / 2)
#define CHUNKS_PER_ROW (SIG_LEN / 4)     // 4096 float4 chunks per row

typedef float f32x2 __attribute__((ext_vector_type(2)));
typedef float f32x4 __attribute__((ext_vector_type(4)));

__global__ __launch_bounds__(256) void dwt_fwd_kernel(
    const float* __restrict__ input,
    const float* __restrict__ scaling,
    float* __restrict__ details,
    float* __restrict__ approx)
{
    const int c   = blockIdx.x * blockDim.x + threadIdx.x;  // chunk id
    const int row = c >> 12;                                // / CHUNKS_PER_ROW
    const int cl  = c & (CHUNKS_PER_ROW - 1);
    const int p   = cl << 2;                                // first input float

    // Filter taps: uniform address -> scalar loads.
    float h[8], w[8];
#pragma unroll
    for (int k = 0; k < 8; ++k) h[k] = scaling[k];
#pragma unroll
    for (int k = 0; k < 8; ++k) w[k] = h[7 - k] * ((k & 1) ? -1.0f : 1.0f);

    const float* rowp = input + (size_t)row * SIG_LEN;

    // y[i] == input[(p - 8 + i) mod SIG_LEN], i = 0..11
    int a0 = p - 8; if (a0 < 0) a0 += SIG_LEN;   // wraps only for cl == 0,1
    int a1 = p - 4; if (a1 < 0) a1 += SIG_LEN;   // wraps only for cl == 0

    const f32x4 hA = *reinterpret_cast<const f32x4*>(rowp + a0); // p-8..p-5
    const f32x4 hB = *reinterpret_cast<const f32x4*>(rowp + a1); // p-4..p-1
    const f32x4 m  = *reinterpret_cast<const f32x4*>(rowp + p);  // p..p+3

    float y[12];
    y[0] = hA.x; y[1] = hA.y; y[2]  = hA.z; y[3]  = hA.w;
    y[4] = hB.x; y[5] = hB.y; y[6]  = hB.z; y[7]  = hB.w;
    y[8] = m.x;  y[9] = m.y;  y[10] = m.z;  y[11] = m.w;

    // Output columns j0 = 2*cl, j1 = 2*cl+1:
    //   out[j0] uses x[p-7..p]   == y[1..8]
    //   out[j1] uses x[p-5..p+2] == y[3..10]
    float d0 = 0.f, a0f = 0.f, d1 = 0.f, a1f = 0.f;
#pragma unroll
    for (int k = 0; k < 8; ++k) {
        const float x0 = y[8 - k];
        const float x1 = y[10 - k];
        d0  = fmaf(w[k], x0, d0);
        a0f = fmaf(h[k], x0, a0f);
        d1  = fmaf(w[k], x1, d1);
        a1f = fmaf(h[k], x1, a1f);
    }

    const size_t obase = (size_t)row * HALF_LEN + (size_t)(cl << 1);
    f32x2 dv; dv.x = d0;  dv.y = d1;
    f32x2 av; av.x = a0f; av.y = a1f;
    __builtin_nontemporal_store(dv, reinterpret_cast<f32x2*>(details + obase));
    __builtin_nontemporal_store(av, reinterpret_cast<f32x2*>(approx + obase));
}

extern "C" void kernel_launch(void* const* d_in, const int* in_sizes, int n_in,
                              void* d_out, int out_size, void* d_ws, size_t ws_size,
                              hipStream_t stream) {
    const float* input   = (const float*)d_in[0];
    const float* scaling = (const float*)d_in[1];
    float* details = (float*)d_out;                                   // output 0
    float* approx  = (float*)d_out + (size_t)N_ROWS * HALF_LEN;       // output 1

    const int total_threads = N_ROWS * CHUNKS_PER_ROW;                // 16,777,216
    const int block = 256;
    const int grid  = total_threads / block;                          // 65,536
    dwt_fwd_kernel<<<grid, block, 0, stream>>>(input, scaling, details, approx);
}